// Round 7
// baseline (3761.677 us; speedup 1.0000x reference)
//
#include <hip/hip_runtime.h>
#include <hip/hip_bf16.h>

#pragma clang fp contract(off)

#define BB 8
#define DD 512
#define LL 4096
#define HH 256
#define NN 2048
#define FEPS 1.1920928955078125e-07f

#define IND_OFF ((size_t)BB * DD * LL)            // 16777216
#define LOSS_OFF (IND_OFF + (size_t)BB * LL)      // 16809984

// ---------------------------------------------------------------- numpy-exact pairwise sums
// numpy pairwise_sum: n<=128 -> 8 accumulators over stride-8, combine
// ((r0+r1)+(r2+r3)) + ((r4+r5)+(r6+r7)); n>128 -> split halves (multiple of 8).
__device__ __forceinline__ float npy_pw128(const float* a) {
    float r0 = 0.f, r1 = 0.f, r2 = 0.f, r3 = 0.f, r4 = 0.f, r5 = 0.f, r6 = 0.f, r7 = 0.f;
    for (int i = 0; i < 128; i += 8) {
        r0 += a[i + 0]; r1 += a[i + 1]; r2 += a[i + 2]; r3 += a[i + 3];
        r4 += a[i + 4]; r5 += a[i + 5]; r6 += a[i + 6]; r7 += a[i + 7];
    }
    return ((r0 + r1) + (r2 + r3)) + ((r4 + r5) + (r6 + r7));
}

__device__ __forceinline__ float npy_pw128_sq(const float* a) {
    float r0 = 0.f, r1 = 0.f, r2 = 0.f, r3 = 0.f, r4 = 0.f, r5 = 0.f, r6 = 0.f, r7 = 0.f;
    for (int i = 0; i < 128; i += 8) {
        float p0 = a[i + 0] * a[i + 0]; float p1 = a[i + 1] * a[i + 1];
        float p2 = a[i + 2] * a[i + 2]; float p3 = a[i + 3] * a[i + 3];
        float p4 = a[i + 4] * a[i + 4]; float p5 = a[i + 5] * a[i + 5];
        float p6 = a[i + 6] * a[i + 6]; float p7 = a[i + 7] * a[i + 7];
        r0 += p0; r1 += p1; r2 += p2; r3 += p3;
        r4 += p4; r5 += p5; r6 += p6; r7 += p7;
    }
    return ((r0 + r1) + (r2 + r3)) + ((r4 + r5) + (r6 + r7));
}

__device__ inline float breduce512_f32(float v, float* sbuf) {
    for (int off = 32; off > 0; off >>= 1) v += __shfl_down(v, off, 64);
    int wid = threadIdx.x >> 6;
    if ((threadIdx.x & 63) == 0) sbuf[wid] = v;
    __syncthreads();
    if (threadIdx.x == 0) {
        float r = 0.f;
#pragma unroll
        for (int i = 0; i < 8; ++i) r += sbuf[i];
        sbuf[0] = r;
    }
    __syncthreads();
    float r = sbuf[0];
    __syncthreads();
    return r;
}

__device__ inline double breduce256_f64(double v, double* dbuf) {
    for (int off = 32; off > 0; off >>= 1) v += __shfl_down(v, off, 64);
    int wid = threadIdx.x >> 6, lane = threadIdx.x & 63;
    if (lane == 0) dbuf[wid] = v;
    __syncthreads();
    if (threadIdx.x == 0) dbuf[0] = dbuf[0] + dbuf[1] + dbuf[2] + dbuf[3];
    __syncthreads();
    double r = dbuf[0];
    __syncthreads();
    return r;
}

// ---------------------------------------------------------------- prep: f32, numpy-exact rounding
// blocks [0,256): w_in rows -> whT[d][h] = w/(norm512+eps)  (elementwise f32 divide)
// blocks [256,768): w_out rows -> woT[h][d] = w/(norm256+eps)
// blocks [768,2816): codebook rows -> cbn[n][h] = cb * (1/sqrtf(mean+eps))
__global__ __launch_bounds__(256) void prep_kernel(const float* __restrict__ w_in,
                                                   const float* __restrict__ codebook,
                                                   const float* __restrict__ w_out,
                                                   float* __restrict__ whT,
                                                   float* __restrict__ cbn,
                                                   float* __restrict__ woT) {
    __shared__ float srow[512];
    __shared__ float sden;
    const int blk = blockIdx.x;
    const int t = threadIdx.x;
    if (blk < HH) {
        const float* row = w_in + (size_t)blk * DD;
        float a = row[t], b = row[t + 256];
        srow[t] = a * a;
        srow[t + 256] = b * b;
        __syncthreads();
        if (t == 0) {
            float ss = (npy_pw128(srow) + npy_pw128(srow + 128)) +
                       (npy_pw128(srow + 256) + npy_pw128(srow + 384));
            sden = sqrtf(ss) + FEPS;
        }
        __syncthreads();
        float den = sden;
        whT[(size_t)t * HH + blk] = a / den;
        whT[(size_t)(t + 256) * HH + blk] = b / den;
    } else if (blk < HH + DD) {
        const int d = blk - HH;
        const float* row = w_out + (size_t)d * HH;
        float a = row[t];
        srow[t] = a * a;
        __syncthreads();
        if (t == 0) {
            float ss = npy_pw128(srow) + npy_pw128(srow + 128);
            sden = sqrtf(ss) + FEPS;
        }
        __syncthreads();
        woT[(size_t)t * DD + d] = a / sden;
    } else {
        const int n = blk - HH - DD;
        const float* row = codebook + (size_t)n * HH;
        float a = row[t];
        srow[t] = a * a;
        __syncthreads();
        if (t == 0) {
            float ss = npy_pw128(srow) + npy_pw128(srow + 128);
            float m = ss / 256.0f;            // exact (pow2)
            sden = 1.0f / sqrtf(m + FEPS);    // lax.rsqrt ~ 1/sqrt
        }
        __syncthreads();
        cbn[(size_t)n * HH + t] = a * sden;
    }
}

// ---------------------------------------------------------------- fused: gemm1+rms+sim/argmax+loss
// grid (LL/64, BB), 512 threads. All-f32, np-mimicking:
//  h[l][o] = seqFMA_k(z*what) / sqrtf(512), rounded to f32 in hsm
//  rms scale via numpy-pairwise mean of squares, s = 1/sqrtf(m+eps), h_n = h*s
//  sim  = seqFMA_k(h_n * cbn), argmax = first max
__global__ __launch_bounds__(512) void fused_kernel(const float* __restrict__ z,
                                                    const float* __restrict__ whT,
                                                    const float* __restrict__ cbn,
                                                    int* __restrict__ inds_i,
                                                    float* __restrict__ partials) {
    __shared__ float smem[16896];   // union: phase1 zT[32][64]@0 + wT[32][256]@2048 ; phase2 hsm[64][264]
    __shared__ float scl[64];
    __shared__ int   ind_sm[64];
    __shared__ float sbuf[8];

    float* zT  = smem;          // [kk][c]  stride 64
    float* wT  = smem + 2048;   // [kk][h]  stride 256
    float* hsm = smem;          // [r][k]   stride 264

    const int b = blockIdx.y;
    const int l0 = blockIdx.x * 64;
    const int t = threadIdx.x;
    const int tl = t & 15, th = t >> 4;      // rows tl*4+il ; h-dims th*8+j
    const int bid = blockIdx.y * gridDim.x + blockIdx.x;

    // ---------------- phase 1: f32 seq-FMA GEMM (k ascending, one chain per output)
    float acc[4][8];
#pragma unroll
    for (int i = 0; i < 4; ++i)
#pragma unroll
        for (int j = 0; j < 8; ++j) acc[i][j] = 0.f;
    const float* zb = z + (size_t)b * DD * LL;
    for (int d0 = 0; d0 < DD; d0 += 32) {
        __syncthreads();
        {   // zT: 2048 floats = 512 x float4
            int kk = t >> 4, c4 = t & 15;
            *(float4*)&zT[kk * 64 + c4 * 4] =
                *(const float4*)(zb + (size_t)(d0 + kk) * LL + l0 + c4 * 4);
        }
#pragma unroll
        for (int r = 0; r < 4; ++r) {   // wT: 8192 floats = 512 x 4 float4
            int idx = r * 512 + t;
            int kk = idx >> 6, h4 = idx & 63;
            *(float4*)&wT[kk * 256 + h4 * 4] =
                *(const float4*)(whT + (size_t)(d0 + kk) * HH + h4 * 4);
        }
        __syncthreads();
#pragma unroll 8
        for (int kk = 0; kk < 32; ++kk) {
            float4 zv = *(const float4*)&zT[kk * 64 + tl * 4];
            float zz[4] = {zv.x, zv.y, zv.z, zv.w};
            float4 wa = *(const float4*)&wT[kk * 256 + th * 8];
            float4 wb = *(const float4*)&wT[kk * 256 + th * 8 + 4];
            float ww[8] = {wa.x, wa.y, wa.z, wa.w, wb.x, wb.y, wb.z, wb.w};
#pragma unroll
            for (int il = 0; il < 4; ++il)
#pragma unroll
                for (int j = 0; j < 8; ++j)
                    acc[il][j] = fmaf(zz[il], ww[j], acc[il][j]);
        }
    }
    __syncthreads();   // all phase-1 LDS reads complete before hsm overwrite

    // ---------------- phase 2: h = acc / sqrt(512) (f32 round) -> hsm raw
    const float SQ512 = sqrtf(512.0f);
#pragma unroll
    for (int il = 0; il < 4; ++il) {
        int row = tl * 4 + il;
#pragma unroll
        for (int j = 0; j < 8; ++j)
            hsm[row * 264 + th * 8 + j] = acc[il][j] / SQ512;
    }
    __syncthreads();
    if (t < 64) {   // numpy-pairwise mean of squares over the stored f32 h
        const float* hr = &hsm[t * 264];
        float ss = npy_pw128_sq(hr) + npy_pw128_sq(hr + 128);
        float m = ss / 256.0f;             // exact
        scl[t] = 1.0f / sqrtf(m + FEPS);
    }
    __syncthreads();
    {   // h_n = h * s, in place (f32 round). 512 threads x 32 elems
        int row = t >> 3, c0 = (t & 7) * 32;
        float s = scl[row];
        float* hp = &hsm[row * 264 + c0];
#pragma unroll
        for (int k = 0; k < 32; ++k) hp[k] = hp[k] * s;
    }
    __syncthreads();

    // ---------------- phase 3: f32 seq-FMA sim scan, first-max argmax (FINAL decision)
    {
        const int p = t >> 4;          // 32 row-pairs
        const int tn = t & 15;         // 16 n-threads x 128 contiguous codes
        const int r0 = p * 2;
        const float* h0p = &hsm[r0 * 264];
        const float* h1p = &hsm[(r0 + 1) * 264];
        float b1[2] = {-3.4e38f, -3.4e38f};
        int i1[2] = {0, 0};
#pragma unroll 1
        for (int g = 0; g < 16; ++g) {
            const int n0 = tn * 128 + g * 8;
            const float* crow = cbn + (size_t)n0 * HH;
            float a8[2][8];
#pragma unroll
            for (int il = 0; il < 2; ++il)
#pragma unroll
                for (int j = 0; j < 8; ++j) a8[il][j] = 0.f;
#pragma unroll 2
            for (int k = 0; k < HH; k += 4) {
                float4 h0 = *(const float4*)&h0p[k];
                float4 h1 = *(const float4*)&h1p[k];
#pragma unroll
                for (int j = 0; j < 8; ++j) {
                    float4 cv = *(const float4*)(crow + (size_t)j * HH + k);
                    float s0 = a8[0][j];
                    s0 = fmaf(h0.x, cv.x, s0); s0 = fmaf(h0.y, cv.y, s0);
                    s0 = fmaf(h0.z, cv.z, s0); s0 = fmaf(h0.w, cv.w, s0);
                    a8[0][j] = s0;
                    float s1 = a8[1][j];
                    s1 = fmaf(h1.x, cv.x, s1); s1 = fmaf(h1.y, cv.y, s1);
                    s1 = fmaf(h1.z, cv.z, s1); s1 = fmaf(h1.w, cv.w, s1);
                    a8[1][j] = s1;
                }
            }
#pragma unroll
            for (int il = 0; il < 2; ++il)
#pragma unroll
                for (int j = 0; j < 8; ++j) {
                    float v = a8[il][j];
                    if (v > b1[il]) { b1[il] = v; i1[il] = n0 + j; }  // strict > = first max
                }
        }
        // butterfly first-max merge across the 16 tn-lanes
#pragma unroll
        for (int m = 1; m < 16; m <<= 1) {
#pragma unroll
            for (int il = 0; il < 2; ++il) {
                float ob = __shfl_xor(b1[il], m, 16);
                int   oi = __shfl_xor(i1[il], m, 16);
                if (ob > b1[il] || (ob == b1[il] && oi < i1[il])) {
                    b1[il] = ob; i1[il] = oi;
                }
            }
        }
        if (tn == 0) {
#pragma unroll
            for (int il = 0; il < 2; ++il) {
                ind_sm[r0 + il] = i1[il];
                inds_i[b * LL + l0 + r0 + il] = i1[il];
            }
        }
    }
    __syncthreads();

    // ---------------- phase 4: loss partial
    {
        int rr = t >> 3, kg = t & 7;
        const float* cq = cbn + (size_t)ind_sm[rr] * HH;
        const float* hr = &hsm[rr * 264];
        float s = 0.f;
#pragma unroll
        for (int k = kg * 32; k < kg * 32 + 32; k += 4) {
            float4 cv = *(const float4*)(cq + k);
            float4 hv = *(const float4*)(hr + k);
            float e0 = cv.x - hv.x, e1 = cv.y - hv.y;
            float e2 = cv.z - hv.z, e3 = cv.w - hv.w;
            s = fmaf(e0, e0, s); s = fmaf(e1, e1, s);
            s = fmaf(e2, e2, s); s = fmaf(e3, e3, s);
        }
        s = breduce512_f32(s, sbuf);
        if (t == 0) partials[bid] = s;
    }
}

// ---------------------------------------------------------------- loss final
__global__ __launch_bounds__(256) void loss_final_kernel(const float* __restrict__ partials,
                                                         float* __restrict__ out_f32) {
    __shared__ double dbuf[8];
    const int t = threadIdx.x;
    double v = (double)partials[t] + (double)partials[t + 256];
    double s = breduce256_f64(v, dbuf);
    if (t == 0) {
        double mean = s / (double)((size_t)BB * LL * HH);
        out_f32[LOSS_OFF] = (float)(mean * 1.25);
    }
}

// ---------------------------------------------------------------- inds epilogue
__global__ __launch_bounds__(256) void epilogue_kernel(const int* __restrict__ inds_i,
                                                       float* __restrict__ out_f32) {
    int idx = blockIdx.x * 256 + threadIdx.x;
    if (idx < BB * LL) out_f32[IND_OFF + idx] = (float)inds_i[idx];
}

// ---------------------------------------------------------------- gemm_out
__global__ __launch_bounds__(256) void gemm_out_kernel(const float* __restrict__ cbn,
                                                       const int* __restrict__ inds_i,
                                                       const float* __restrict__ woT,
                                                       float* __restrict__ out_f32) {
    __shared__ float zqT[32][68];
    __shared__ float wo[32][64];
    __shared__ int inds_s[64];
    const int b = blockIdx.z;
    const int d0 = blockIdx.y * 64;
    const int l0 = blockIdx.x * 64;
    const int t = threadIdx.x;
    const int tl = t & 15, td = t >> 4;
    if (t < 64) {
        int ii = inds_i[b * LL + l0 + t];
        inds_s[t] = min(max(ii, 0), NN - 1);
    }
    float acc[4][4];
#pragma unroll
    for (int i = 0; i < 4; ++i)
#pragma unroll
        for (int j = 0; j < 4; ++j) acc[i][j] = 0.f;
    for (int k0 = 0; k0 < HH; k0 += 32) {
        __syncthreads();
#pragma unroll
        for (int r = 0; r < 2; ++r) {
            int idx = r * 256 + t;
            int li = idx >> 3, k4 = idx & 7;
            float4 v = *(const float4*)(cbn + (size_t)inds_s[li] * HH + k0 + k4 * 4);
            zqT[k4 * 4 + 0][li] = v.x;
            zqT[k4 * 4 + 1][li] = v.y;
            zqT[k4 * 4 + 2][li] = v.z;
            zqT[k4 * 4 + 3][li] = v.w;
        }
#pragma unroll
        for (int r = 0; r < 2; ++r) {
            int idx = r * 256 + t;
            int kk = idx >> 4, d4 = idx & 15;
            *(float4*)&wo[kk][d4 * 4] = *(const float4*)(woT + (size_t)(k0 + kk) * DD + d0 + d4 * 4);
        }
        __syncthreads();
#pragma unroll 8
        for (int kk = 0; kk < 32; ++kk) {
            float4 zv = *(const float4*)&zqT[kk][tl * 4];
            float4 wv = *(const float4*)&wo[kk][td * 4];
            float zz[4] = {zv.x, zv.y, zv.z, zv.w};
            float ww[4] = {wv.x, wv.y, wv.z, wv.w};
#pragma unroll
            for (int il = 0; il < 4; ++il)
#pragma unroll
                for (int jd = 0; jd < 4; ++jd)
                    acc[il][jd] = fmaf(zz[il], ww[jd], acc[il][jd]);
        }
    }
    const float SQ256 = sqrtf(256.0f);   // exact 16
#pragma unroll
    for (int jd = 0; jd < 4; ++jd) {
        int d = d0 + td * 4 + jd;
        float4 v;
        v.x = acc[0][jd] / SQ256;
        v.y = acc[1][jd] / SQ256;
        v.z = acc[2][jd] / SQ256;
        v.w = acc[3][jd] / SQ256;
        *(float4*)(out_f32 + ((size_t)b * DD + d) * LL + l0 + tl * 4) = v;
    }
}

extern "C" void kernel_launch(void* const* d_in, const int* in_sizes, int n_in,
                              void* d_out, int out_size, void* d_ws, size_t ws_size,
                              hipStream_t stream) {
    const float* z        = (const float*)d_in[0];
    const float* w_in     = (const float*)d_in[1];
    const float* codebook = (const float*)d_in[2];
    const float* w_out    = (const float*)d_in[3];

    char* ws = (char*)d_ws;
    size_t off = 0;
    float* whT = (float*)(ws + off); off += (size_t)DD * HH * 4;
    float* cbn = (float*)(ws + off); off += (size_t)NN * HH * 4;
    float* woT = (float*)(ws + off); off += (size_t)HH * DD * 4;
    int* inds_i = (int*)(ws + off);  off += (size_t)BB * LL * 4;
    float* partials = (float*)(ws + off); off += 512 * 4;

    float* out_f32 = (float*)d_out;

    prep_kernel<<<HH + DD + NN, 256, 0, stream>>>(w_in, codebook, w_out, whT, cbn, woT);
    fused_kernel<<<dim3(LL / 64, BB), 512, 0, stream>>>(z, whT, cbn, inds_i, partials);
    loss_final_kernel<<<1, 256, 0, stream>>>(partials, out_f32);
    epilogue_kernel<<<(BB * LL + 255) / 256, 256, 0, stream>>>(inds_i, out_f32);
    gemm_out_kernel<<<dim3(LL / 64, DD / 64, BB), 256, 0, stream>>>(cbn, inds_i, woT, out_f32);
}

// Round 8
// 1121.763 us; speedup vs baseline: 3.3534x; 3.3534x over previous
//
#include <hip/hip_runtime.h>
#include <hip/hip_bf16.h>

#pragma clang fp contract(off)

#define BB 8
#define DD 512
#define LL 4096
#define HH 256
#define NN 2048
#define FEPS 1.1920928955078125e-07f

#define IND_OFF ((size_t)BB * DD * LL)            // 16777216
#define LOSS_OFF (IND_OFF + (size_t)BB * LL)      // 16809984

// ---------------------------------------------------------------- numpy-exact pairwise sums
__device__ __forceinline__ float npy_pw128(const float* a) {
    float r0 = 0.f, r1 = 0.f, r2 = 0.f, r3 = 0.f, r4 = 0.f, r5 = 0.f, r6 = 0.f, r7 = 0.f;
    for (int i = 0; i < 128; i += 8) {
        r0 += a[i + 0]; r1 += a[i + 1]; r2 += a[i + 2]; r3 += a[i + 3];
        r4 += a[i + 4]; r5 += a[i + 5]; r6 += a[i + 6]; r7 += a[i + 7];
    }
    return ((r0 + r1) + (r2 + r3)) + ((r4 + r5) + (r6 + r7));
}

__device__ __forceinline__ float npy_pw128_sq(const float* a) {
    float r0 = 0.f, r1 = 0.f, r2 = 0.f, r3 = 0.f, r4 = 0.f, r5 = 0.f, r6 = 0.f, r7 = 0.f;
    for (int i = 0; i < 128; i += 8) {
        float p0 = a[i + 0] * a[i + 0]; float p1 = a[i + 1] * a[i + 1];
        float p2 = a[i + 2] * a[i + 2]; float p3 = a[i + 3] * a[i + 3];
        float p4 = a[i + 4] * a[i + 4]; float p5 = a[i + 5] * a[i + 5];
        float p6 = a[i + 6] * a[i + 6]; float p7 = a[i + 7] * a[i + 7];
        r0 += p0; r1 += p1; r2 += p2; r3 += p3;
        r4 += p4; r5 += p5; r6 += p6; r7 += p7;
    }
    return ((r0 + r1) + (r2 + r3)) + ((r4 + r5) + (r6 + r7));
}

__device__ inline float breduce512_f32(float v, float* sbuf) {
    for (int off = 32; off > 0; off >>= 1) v += __shfl_down(v, off, 64);
    int wid = threadIdx.x >> 6;
    if ((threadIdx.x & 63) == 0) sbuf[wid] = v;
    __syncthreads();
    if (threadIdx.x == 0) {
        float r = 0.f;
#pragma unroll
        for (int i = 0; i < 8; ++i) r += sbuf[i];
        sbuf[0] = r;
    }
    __syncthreads();
    float r = sbuf[0];
    __syncthreads();
    return r;
}

__device__ inline double breduce256_f64(double v, double* dbuf) {
    for (int off = 32; off > 0; off >>= 1) v += __shfl_down(v, off, 64);
    int wid = threadIdx.x >> 6, lane = threadIdx.x & 63;
    if (lane == 0) dbuf[wid] = v;
    __syncthreads();
    if (threadIdx.x == 0) dbuf[0] = dbuf[0] + dbuf[1] + dbuf[2] + dbuf[3];
    __syncthreads();
    double r = dbuf[0];
    __syncthreads();
    return r;
}

// ---------------------------------------------------------------- prep (unchanged, validated)
__global__ __launch_bounds__(256) void prep_kernel(const float* __restrict__ w_in,
                                                   const float* __restrict__ codebook,
                                                   const float* __restrict__ w_out,
                                                   float* __restrict__ whT,
                                                   float* __restrict__ cbn,
                                                   float* __restrict__ woT) {
    __shared__ float srow[512];
    __shared__ float sden;
    const int blk = blockIdx.x;
    const int t = threadIdx.x;
    if (blk < HH) {
        const float* row = w_in + (size_t)blk * DD;
        float a = row[t], b = row[t + 256];
        srow[t] = a * a;
        srow[t + 256] = b * b;
        __syncthreads();
        if (t == 0) {
            float ss = (npy_pw128(srow) + npy_pw128(srow + 128)) +
                       (npy_pw128(srow + 256) + npy_pw128(srow + 384));
            sden = sqrtf(ss) + FEPS;
        }
        __syncthreads();
        float den = sden;
        whT[(size_t)t * HH + blk] = a / den;
        whT[(size_t)(t + 256) * HH + blk] = b / den;
    } else if (blk < HH + DD) {
        const int d = blk - HH;
        const float* row = w_out + (size_t)d * HH;
        float a = row[t];
        srow[t] = a * a;
        __syncthreads();
        if (t == 0) {
            float ss = npy_pw128(srow) + npy_pw128(srow + 128);
            sden = sqrtf(ss) + FEPS;
        }
        __syncthreads();
        woT[(size_t)t * DD + d] = a / sden;
    } else {
        const int n = blk - HH - DD;
        const float* row = codebook + (size_t)n * HH;
        float a = row[t];
        srow[t] = a * a;
        __syncthreads();
        if (t == 0) {
            float ss = npy_pw128(srow) + npy_pw128(srow + 128);
            float m = ss / 256.0f;
            sden = 1.0f / sqrtf(m + FEPS);
        }
        __syncthreads();
        cbn[(size_t)n * HH + t] = a * sden;
    }
}

// ---------------------------------------------------------------- fused: 32-row blocks, LDS-staged codebook
// grid (LL/32, BB), 512 threads. Bit-identical decision arithmetic to the
// validated round-7 kernel: same k-ascending seq-FMA chains, same npy
// pairwise rms, same strict-> first-max argmax. Only data movement changed.
__global__ __launch_bounds__(512) void fused_kernel(const float* __restrict__ z,
                                                    const float* __restrict__ whT,
                                                    const float* __restrict__ cbn,
                                                    int* __restrict__ inds_i,
                                                    float* __restrict__ partials) {
    __shared__ float smem[17536];   // 70.1KB: union{ zT[32][32]@0 + wT[32][256]@1024 | hsm[32][264]@0 } + cbt[32][260]@9216
    __shared__ float rtmp[64];
    __shared__ float scl[32];
    __shared__ int   ind_sm[32];
    __shared__ float sbuf[8];

    float* zT  = smem;              // [kk][l]   stride 32
    float* wT  = smem + 1024;       // [kk][h]   stride 256
    float* hsm = smem;              // [row][k]  stride 264
    float* cbt = smem + 9216;       // [code][k] stride 260

    const int b = blockIdx.y;
    const int l0 = blockIdx.x * 32;
    const int t = threadIdx.x;
    const int bid = blockIdx.y * gridDim.x + blockIdx.x;

    // ---------------- phase 1: f32 seq-FMA GEMM, thread = 2 rows x 8 h
    const int rp = t & 15;          // row pair -> rows rp*2, rp*2+1
    const int hg = t >> 4;          // 32 groups of 8 h
    float acc[2][8];
#pragma unroll
    for (int i = 0; i < 2; ++i)
#pragma unroll
        for (int j = 0; j < 8; ++j) acc[i][j] = 0.f;
    const float* zb = z + (size_t)b * DD * LL;
    for (int d0 = 0; d0 < DD; d0 += 32) {
        __syncthreads();
        {   // zT: 1024 floats = 512 x float2
            int kk = t >> 4, c2 = t & 15;
            *(float2*)&zT[kk * 32 + c2 * 2] =
                *(const float2*)(zb + (size_t)(d0 + kk) * LL + l0 + c2 * 2);
        }
#pragma unroll
        for (int r = 0; r < 4; ++r) {   // wT: 8192 floats = 512 x 4 float4
            int idx = r * 512 + t;
            int kk = idx >> 6, h4 = idx & 63;
            *(float4*)&wT[kk * 256 + h4 * 4] =
                *(const float4*)(whT + (size_t)(d0 + kk) * HH + h4 * 4);
        }
        __syncthreads();
#pragma unroll 8
        for (int kk = 0; kk < 32; ++kk) {
            float2 zv = *(const float2*)&zT[kk * 32 + rp * 2];
            float4 wa = *(const float4*)&wT[kk * 256 + hg * 8];
            float4 wb = *(const float4*)&wT[kk * 256 + hg * 8 + 4];
            float ww[8] = {wa.x, wa.y, wa.z, wa.w, wb.x, wb.y, wb.z, wb.w};
#pragma unroll
            for (int j = 0; j < 8; ++j) {
                acc[0][j] = fmaf(zv.x, ww[j], acc[0][j]);
                acc[1][j] = fmaf(zv.y, ww[j], acc[1][j]);
            }
        }
    }
    __syncthreads();   // phase-1 LDS reads done before hsm overwrite

    // ---------------- phase 2: h = acc / sqrt(512) -> hsm; npy rms; hn in place
    const float SQ512 = sqrtf(512.0f);
#pragma unroll
    for (int il = 0; il < 2; ++il) {
        int row = rp * 2 + il;
#pragma unroll
        for (int j = 0; j < 8; ++j)
            hsm[row * 264 + hg * 8 + j] = acc[il][j] / SQ512;
    }
    __syncthreads();
    if (t < 64) {   // two pw128 halves per row, np combine order
        int row = t >> 1, half = t & 1;
        rtmp[t] = npy_pw128_sq(&hsm[row * 264 + half * 128]);
    }
    __syncthreads();
    if (t < 32) {
        float ss = rtmp[t * 2] + rtmp[t * 2 + 1];
        float m = ss / 256.0f;
        scl[t] = 1.0f / sqrtf(m + FEPS);
    }
    __syncthreads();
    {   // h_n = h * s in place: 512 threads x 16 elems
        int row = t >> 4, c0 = (t & 15) * 16;
        float s = scl[row];
        float* hp = &hsm[row * 264 + c0];
#pragma unroll
        for (int k = 0; k < 16; ++k) hp[k] = hp[k] * s;
    }

    // ---------------- phase 3: LDS-staged sim scan, first-max argmax
    const int pr = t >> 5;          // 16 row pairs
    const int cq = t & 31;          // 32 code slots per tile
    const float* h0p = &hsm[(pr * 2) * 264];
    const float* h1p = &hsm[(pr * 2 + 1) * 264];
    float b1[2] = {-3.4e38f, -3.4e38f};
    int i1[2] = {0, 0};
#pragma unroll 1
    for (int tile = 0; tile < 64; ++tile) {
        const int n0 = tile * 32;
        __syncthreads();   // previous tile's cbt reads complete
#pragma unroll
        for (int r = 0; r < 4; ++r) {   // stage 32 codes x 256 k, coalesced
            int idx = r * 512 + t;
            int code = idx >> 6, kp = idx & 63;
            *(float4*)&cbt[code * 260 + kp * 4] =
                *(const float4*)(cbn + (size_t)(n0 + code) * HH + kp * 4);
        }
        __syncthreads();
        const float* crow = &cbt[cq * 260];
        float a0 = 0.f, a1 = 0.f;
#pragma unroll 4
        for (int k = 0; k < HH; k += 4) {
            float4 cv = *(const float4*)&crow[k];
            float4 h0 = *(const float4*)&h0p[k];
            float4 h1 = *(const float4*)&h1p[k];
            a0 = fmaf(h0.x, cv.x, a0); a0 = fmaf(h0.y, cv.y, a0);
            a0 = fmaf(h0.z, cv.z, a0); a0 = fmaf(h0.w, cv.w, a0);
            a1 = fmaf(h1.x, cv.x, a1); a1 = fmaf(h1.y, cv.y, a1);
            a1 = fmaf(h1.z, cv.z, a1); a1 = fmaf(h1.w, cv.w, a1);
        }
        int n = n0 + cq;   // per-thread n ascending across tiles -> strict > = first max
        if (a0 > b1[0]) { b1[0] = a0; i1[0] = n; }
        if (a1 > b1[1]) { b1[1] = a1; i1[1] = n; }
    }
    // butterfly first-max merge across the 32 cq-lanes (same wave half)
#pragma unroll
    for (int m = 1; m < 32; m <<= 1) {
#pragma unroll
        for (int il = 0; il < 2; ++il) {
            float ob = __shfl_xor(b1[il], m, 32);
            int   oi = __shfl_xor(i1[il], m, 32);
            if (ob > b1[il] || (ob == b1[il] && oi < i1[il])) {
                b1[il] = ob; i1[il] = oi;
            }
        }
    }
    if (cq == 0) {
#pragma unroll
        for (int il = 0; il < 2; ++il) {
            ind_sm[pr * 2 + il] = i1[il];
            inds_i[b * LL + l0 + pr * 2 + il] = i1[il];
        }
    }
    __syncthreads();

    // ---------------- phase 4: loss partial (32 rows x 256 k, 512 threads)
    {
        int rr = t >> 4, kg = t & 15;
        const float* cq2 = cbn + (size_t)ind_sm[rr] * HH;
        const float* hr = &hsm[rr * 264];
        float s = 0.f;
#pragma unroll
        for (int k = kg * 16; k < kg * 16 + 16; k += 4) {
            float4 cv = *(const float4*)(cq2 + k);
            float4 hv = *(const float4*)(hr + k);
            float e0 = cv.x - hv.x, e1 = cv.y - hv.y;
            float e2 = cv.z - hv.z, e3 = cv.w - hv.w;
            s = fmaf(e0, e0, s); s = fmaf(e1, e1, s);
            s = fmaf(e2, e2, s); s = fmaf(e3, e3, s);
        }
        s = breduce512_f32(s, sbuf);
        if (t == 0) partials[bid] = s;
    }
}

// ---------------------------------------------------------------- loss final (1024 partials)
__global__ __launch_bounds__(256) void loss_final_kernel(const float* __restrict__ partials,
                                                         float* __restrict__ out_f32) {
    __shared__ double dbuf[8];
    const int t = threadIdx.x;
    double v = ((double)partials[t] + (double)partials[t + 256]) +
               ((double)partials[t + 512] + (double)partials[t + 768]);
    double s = breduce256_f64(v, dbuf);
    if (t == 0) {
        double mean = s / (double)((size_t)BB * LL * HH);
        out_f32[LOSS_OFF] = (float)(mean * 1.25);
    }
}

// ---------------------------------------------------------------- inds epilogue
__global__ __launch_bounds__(256) void epilogue_kernel(const int* __restrict__ inds_i,
                                                       float* __restrict__ out_f32) {
    int idx = blockIdx.x * 256 + threadIdx.x;
    if (idx < BB * LL) out_f32[IND_OFF + idx] = (float)inds_i[idx];
}

// ---------------------------------------------------------------- gemm_out (unchanged)
__global__ __launch_bounds__(256) void gemm_out_kernel(const float* __restrict__ cbn,
                                                       const int* __restrict__ inds_i,
                                                       const float* __restrict__ woT,
                                                       float* __restrict__ out_f32) {
    __shared__ float zqT[32][68];
    __shared__ float wo[32][64];
    __shared__ int inds_s[64];
    const int b = blockIdx.z;
    const int d0 = blockIdx.y * 64;
    const int l0 = blockIdx.x * 64;
    const int t = threadIdx.x;
    const int tl = t & 15, td = t >> 4;
    if (t < 64) {
        int ii = inds_i[b * LL + l0 + t];
        inds_s[t] = min(max(ii, 0), NN - 1);
    }
    float acc[4][4];
#pragma unroll
    for (int i = 0; i < 4; ++i)
#pragma unroll
        for (int j = 0; j < 4; ++j) acc[i][j] = 0.f;
    for (int k0 = 0; k0 < HH; k0 += 32) {
        __syncthreads();
#pragma unroll
        for (int r = 0; r < 2; ++r) {
            int idx = r * 256 + t;
            int li = idx >> 3, k4 = idx & 7;
            float4 v = *(const float4*)(cbn + (size_t)inds_s[li] * HH + k0 + k4 * 4);
            zqT[k4 * 4 + 0][li] = v.x;
            zqT[k4 * 4 + 1][li] = v.y;
            zqT[k4 * 4 + 2][li] = v.z;
            zqT[k4 * 4 + 3][li] = v.w;
        }
#pragma unroll
        for (int r = 0; r < 2; ++r) {
            int idx = r * 256 + t;
            int kk = idx >> 4, d4 = idx & 15;
            *(float4*)&wo[kk][d4 * 4] = *(const float4*)(woT + (size_t)(k0 + kk) * DD + d0 + d4 * 4);
        }
        __syncthreads();
#pragma unroll 8
        for (int kk = 0; kk < 32; ++kk) {
            float4 zv = *(const float4*)&zqT[kk][tl * 4];
            float4 wv = *(const float4*)&wo[kk][td * 4];
            float zz[4] = {zv.x, zv.y, zv.z, zv.w};
            float ww[4] = {wv.x, wv.y, wv.z, wv.w};
#pragma unroll
            for (int il = 0; il < 4; ++il)
#pragma unroll
                for (int jd = 0; jd < 4; ++jd)
                    acc[il][jd] = fmaf(zz[il], ww[jd], acc[il][jd]);
        }
    }
    const float SQ256 = sqrtf(256.0f);
#pragma unroll
    for (int jd = 0; jd < 4; ++jd) {
        int d = d0 + td * 4 + jd;
        float4 v;
        v.x = acc[0][jd] / SQ256;
        v.y = acc[1][jd] / SQ256;
        v.z = acc[2][jd] / SQ256;
        v.w = acc[3][jd] / SQ256;
        *(float4*)(out_f32 + ((size_t)b * DD + d) * LL + l0 + tl * 4) = v;
    }
}

extern "C" void kernel_launch(void* const* d_in, const int* in_sizes, int n_in,
                              void* d_out, int out_size, void* d_ws, size_t ws_size,
                              hipStream_t stream) {
    const float* z        = (const float*)d_in[0];
    const float* w_in     = (const float*)d_in[1];
    const float* codebook = (const float*)d_in[2];
    const float* w_out    = (const float*)d_in[3];

    char* ws = (char*)d_ws;
    size_t off = 0;
    float* whT = (float*)(ws + off); off += (size_t)DD * HH * 4;
    float* cbn = (float*)(ws + off); off += (size_t)NN * HH * 4;
    float* woT = (float*)(ws + off); off += (size_t)HH * DD * 4;
    int* inds_i = (int*)(ws + off);  off += (size_t)BB * LL * 4;
    float* partials = (float*)(ws + off); off += 1024 * 4;

    float* out_f32 = (float*)d_out;

    prep_kernel<<<HH + DD + NN, 256, 0, stream>>>(w_in, codebook, w_out, whT, cbn, woT);
    fused_kernel<<<dim3(LL / 32, BB), 512, 0, stream>>>(z, whT, cbn, inds_i, partials);
    loss_final_kernel<<<1, 256, 0, stream>>>(partials, out_f32);
    epilogue_kernel<<<(BB * LL + 255) / 256, 256, 0, stream>>>(inds_i, out_f32);
    gemm_out_kernel<<<dim3(LL / 64, DD / 64, BB), 256, 0, stream>>>(cbn, inds_i, woT, out_f32);
}

// Round 9
// 684.987 us; speedup vs baseline: 5.4916x; 1.6376x over previous
//
#include <hip/hip_runtime.h>
#include <hip/hip_bf16.h>

#pragma clang fp contract(off)

#define BB 8
#define DD 512
#define LL 4096
#define HH 256
#define NN 2048
#define FEPS 1.1920928955078125e-07f

#define IND_OFF ((size_t)BB * DD * LL)            // 16777216
#define LOSS_OFF (IND_OFF + (size_t)BB * LL)      // 16809984

typedef unsigned short u16;
typedef __attribute__((ext_vector_type(8))) short s8v;     // 8 bf16
typedef __attribute__((ext_vector_type(4))) float f32x4;

__device__ __forceinline__ u16 bf16bits(float x) {
    __hip_bfloat16 h = __float2bfloat16(x);
    return *reinterpret_cast<u16*>(&h);
}
__device__ __forceinline__ float bf16val(u16 b) {
    __hip_bfloat16 h = *reinterpret_cast<__hip_bfloat16*>(&b);
    return __bfloat162float(h);
}

// ---------------------------------------------------------------- numpy-exact pairwise sums
__device__ __forceinline__ float npy_pw128(const float* a) {
    float r0 = 0.f, r1 = 0.f, r2 = 0.f, r3 = 0.f, r4 = 0.f, r5 = 0.f, r6 = 0.f, r7 = 0.f;
    for (int i = 0; i < 128; i += 8) {
        r0 += a[i + 0]; r1 += a[i + 1]; r2 += a[i + 2]; r3 += a[i + 3];
        r4 += a[i + 4]; r5 += a[i + 5]; r6 += a[i + 6]; r7 += a[i + 7];
    }
    return ((r0 + r1) + (r2 + r3)) + ((r4 + r5) + (r6 + r7));
}

__device__ __forceinline__ float npy_pw128_sq(const float* a) {
    float r0 = 0.f, r1 = 0.f, r2 = 0.f, r3 = 0.f, r4 = 0.f, r5 = 0.f, r6 = 0.f, r7 = 0.f;
    for (int i = 0; i < 128; i += 8) {
        float p0 = a[i + 0] * a[i + 0]; float p1 = a[i + 1] * a[i + 1];
        float p2 = a[i + 2] * a[i + 2]; float p3 = a[i + 3] * a[i + 3];
        float p4 = a[i + 4] * a[i + 4]; float p5 = a[i + 5] * a[i + 5];
        float p6 = a[i + 6] * a[i + 6]; float p7 = a[i + 7] * a[i + 7];
        r0 += p0; r1 += p1; r2 += p2; r3 += p3;
        r4 += p4; r5 += p5; r6 += p6; r7 += p7;
    }
    return ((r0 + r1) + (r2 + r3)) + ((r4 + r5) + (r6 + r7));
}

__device__ inline float breduce512_f32(float v, float* sbuf) {
    for (int off = 32; off > 0; off >>= 1) v += __shfl_down(v, off, 64);
    int wid = threadIdx.x >> 6;
    if ((threadIdx.x & 63) == 0) sbuf[wid] = v;
    __syncthreads();
    if (threadIdx.x == 0) {
        float r = 0.f;
#pragma unroll
        for (int i = 0; i < 8; ++i) r += sbuf[i];
        sbuf[0] = r;
    }
    __syncthreads();
    float r = sbuf[0];
    __syncthreads();
    return r;
}

__device__ inline double breduce256_f64(double v, double* dbuf) {
    for (int off = 32; off > 0; off >>= 1) v += __shfl_down(v, off, 64);
    int wid = threadIdx.x >> 6, lane = threadIdx.x & 63;
    if (lane == 0) dbuf[wid] = v;
    __syncthreads();
    if (threadIdx.x == 0) dbuf[0] = dbuf[0] + dbuf[1] + dbuf[2] + dbuf[3];
    __syncthreads();
    double r = dbuf[0];
    __syncthreads();
    return r;
}

// ---------------------------------------------------------------- prep (validated + bf16 hi/lo of cbn)
__global__ __launch_bounds__(256) void prep_kernel(const float* __restrict__ w_in,
                                                   const float* __restrict__ codebook,
                                                   const float* __restrict__ w_out,
                                                   float* __restrict__ whT,
                                                   float* __restrict__ cbn,
                                                   float* __restrict__ woT,
                                                   u16* __restrict__ cb_hi,
                                                   u16* __restrict__ cb_lo) {
    __shared__ float srow[512];
    __shared__ float sden;
    const int blk = blockIdx.x;
    const int t = threadIdx.x;
    if (blk < HH) {
        const float* row = w_in + (size_t)blk * DD;
        float a = row[t], b = row[t + 256];
        srow[t] = a * a;
        srow[t + 256] = b * b;
        __syncthreads();
        if (t == 0) {
            float ss = (npy_pw128(srow) + npy_pw128(srow + 128)) +
                       (npy_pw128(srow + 256) + npy_pw128(srow + 384));
            sden = sqrtf(ss) + FEPS;
        }
        __syncthreads();
        float den = sden;
        whT[(size_t)t * HH + blk] = a / den;
        whT[(size_t)(t + 256) * HH + blk] = b / den;
    } else if (blk < HH + DD) {
        const int d = blk - HH;
        const float* row = w_out + (size_t)d * HH;
        float a = row[t];
        srow[t] = a * a;
        __syncthreads();
        if (t == 0) {
            float ss = npy_pw128(srow) + npy_pw128(srow + 128);
            sden = sqrtf(ss) + FEPS;
        }
        __syncthreads();
        woT[(size_t)t * DD + d] = a / sden;
    } else {
        const int n = blk - HH - DD;
        const float* row = codebook + (size_t)n * HH;
        float a = row[t];
        srow[t] = a * a;
        __syncthreads();
        if (t == 0) {
            float ss = npy_pw128(srow) + npy_pw128(srow + 128);
            float m = ss / 256.0f;
            sden = 1.0f / sqrtf(m + FEPS);
        }
        __syncthreads();
        float v = a * sden;
        cbn[(size_t)n * HH + t] = v;
        u16 hi = bf16bits(v);
        cb_hi[(size_t)n * HH + t] = hi;
        cb_lo[(size_t)n * HH + t] = bf16bits(v - bf16val(hi));
    }
}

// ---------------------------------------------------------------- fused: gemm1+rms + MFMA screen + exact verify + loss
// grid (LL/32, BB), 512 threads.
__global__ __launch_bounds__(512, 4) void fused_kernel(const float* __restrict__ z,
                                                       const float* __restrict__ whT,
                                                       const float* __restrict__ cbn,
                                                       const u16* __restrict__ cb_hi,
                                                       const u16* __restrict__ cb_lo,
                                                       int* __restrict__ inds_i,
                                                       float* __restrict__ partials) {
    __shared__ float smem[9216];        // union: phase1 zT[32][32]@0 + wT[32][256]@1024 | hsm[32][264]@0
    __shared__ u16  hhi[32 * 264];      // bf16 hi of h_n
    __shared__ u16  hlo[32 * 264];      // bf16 lo
    __shared__ float cand_v[32][8][2];
    __shared__ int   cand_i[32][8][2];
    __shared__ int   c4i[32][4];
    __shared__ float exv[32][4];
    __shared__ float rtmp[64];
    __shared__ float scl[32];
    __shared__ int   ind_sm[32];
    __shared__ float sbuf[8];

    float* zT  = smem;              // [kk][l]   stride 32
    float* wT  = smem + 1024;       // [kk][h]   stride 256
    float* hsm = smem;              // [row][k]  stride 264

    const int b = blockIdx.y;
    const int l0 = blockIdx.x * 32;
    const int t = threadIdx.x;
    const int bid = blockIdx.y * gridDim.x + blockIdx.x;

    // ---------------- phase 1: f32 seq-FMA GEMM (validated, bit-exact)
    const int rp = t & 15;
    const int hg = t >> 4;
    float acc[2][8];
#pragma unroll
    for (int i = 0; i < 2; ++i)
#pragma unroll
        for (int j = 0; j < 8; ++j) acc[i][j] = 0.f;
    const float* zb = z + (size_t)b * DD * LL;
    for (int d0 = 0; d0 < DD; d0 += 32) {
        __syncthreads();
        {
            int kk = t >> 4, c2 = t & 15;
            *(float2*)&zT[kk * 32 + c2 * 2] =
                *(const float2*)(zb + (size_t)(d0 + kk) * LL + l0 + c2 * 2);
        }
#pragma unroll
        for (int r = 0; r < 4; ++r) {
            int idx = r * 512 + t;
            int kk = idx >> 6, h4 = idx & 63;
            *(float4*)&wT[kk * 256 + h4 * 4] =
                *(const float4*)(whT + (size_t)(d0 + kk) * HH + h4 * 4);
        }
        __syncthreads();
#pragma unroll 8
        for (int kk = 0; kk < 32; ++kk) {
            float2 zv = *(const float2*)&zT[kk * 32 + rp * 2];
            float4 wa = *(const float4*)&wT[kk * 256 + hg * 8];
            float4 wb = *(const float4*)&wT[kk * 256 + hg * 8 + 4];
            float ww[8] = {wa.x, wa.y, wa.z, wa.w, wb.x, wb.y, wb.z, wb.w};
#pragma unroll
            for (int j = 0; j < 8; ++j) {
                acc[0][j] = fmaf(zv.x, ww[j], acc[0][j]);
                acc[1][j] = fmaf(zv.y, ww[j], acc[1][j]);
            }
        }
    }
    __syncthreads();

    // ---------------- phase 2: h -> hsm; npy rms; h_n in place (validated)
    const float SQ512 = sqrtf(512.0f);
#pragma unroll
    for (int il = 0; il < 2; ++il) {
        int row = rp * 2 + il;
#pragma unroll
        for (int j = 0; j < 8; ++j)
            hsm[row * 264 + hg * 8 + j] = acc[il][j] / SQ512;
    }
    __syncthreads();
    if (t < 64) {
        int row = t >> 1, half = t & 1;
        rtmp[t] = npy_pw128_sq(&hsm[row * 264 + half * 128]);
    }
    __syncthreads();
    if (t < 32) {
        float ss = rtmp[t * 2] + rtmp[t * 2 + 1];
        float m = ss / 256.0f;
        scl[t] = 1.0f / sqrtf(m + FEPS);
    }
    __syncthreads();
    {
        int row = t >> 4, c0 = (t & 15) * 16;
        float s = scl[row];
        float* hp = &hsm[row * 264 + c0];
#pragma unroll
        for (int k = 0; k < 16; ++k) hp[k] = hp[k] * s;
    }
    __syncthreads();

    // ---------------- phase 2b: bf16 hi/lo split of h_n
    {
        int row = t >> 4, c0 = (t & 15) * 16;
        const float* hp = &hsm[row * 264 + c0];
        u16* hh = &hhi[row * 264 + c0];
        u16* hl = &hlo[row * 264 + c0];
#pragma unroll
        for (int k = 0; k < 16; ++k) {
            float x = hp[k];
            u16 hi = bf16bits(x);
            hh[k] = hi;
            hl[k] = bf16bits(x - bf16val(hi));
        }
    }
    __syncthreads();

    // ---------------- phase 3a: MFMA screen -> per-wave top-2 per row
    {
        const int lane = t & 63;
        const int wid = t >> 6;          // 8 waves
        const int col = lane & 15;       // A-row within M-tile / B-code within N-tile
        const int kg = lane >> 4;        // k-group: k = s*32 + kg*8 + e
#pragma unroll 1
        for (int Mt = 0; Mt < 2; ++Mt) {
            const int arow = Mt * 16 + col;
            s8v ah[8];
#pragma unroll
            for (int s = 0; s < 8; ++s)
                ah[s] = *(const s8v*)&hhi[arow * 264 + s * 32 + kg * 8];
            // per-lane top-2 per rowslot j (rows kg*4+j of this M-tile)
            float v0[4], v1[4]; int i0[4], i1[4];
#pragma unroll
            for (int j = 0; j < 4; ++j) { v0[j] = -3.4e38f; v1[j] = -3.4e38f; i0[j] = 0; i1[j] = 0; }
#pragma unroll 1
            for (int it = 0; it < 16; ++it) {
                const int n0 = (wid * 16 + it) * 16;
                const u16* cbh = cb_hi + (size_t)(n0 + col) * HH;
                const u16* cbl = cb_lo + (size_t)(n0 + col) * HH;
                f32x4 a0 = {0.f, 0.f, 0.f, 0.f}, a1 = a0, a2 = a0;
#pragma unroll
                for (int s = 0; s < 8; ++s) {
                    s8v bh = *(const s8v*)(cbh + s * 32 + kg * 8);
                    s8v bl = *(const s8v*)(cbl + s * 32 + kg * 8);
                    s8v al = *(const s8v*)&hlo[arow * 264 + s * 32 + kg * 8];
                    a0 = __builtin_amdgcn_mfma_f32_16x16x32_bf16(ah[s], bh, a0, 0, 0, 0);
                    a1 = __builtin_amdgcn_mfma_f32_16x16x32_bf16(ah[s], bl, a1, 0, 0, 0);
                    a2 = __builtin_amdgcn_mfma_f32_16x16x32_bf16(al, bh, a2, 0, 0, 0);
                }
                const int n = n0 + col;
#pragma unroll
                for (int j = 0; j < 4; ++j) {
                    float v = (a0[j] + a1[j]) + a2[j];
                    bool g0 = v > v0[j], g1 = v > v1[j];
                    v1[j] = g0 ? v0[j] : (g1 ? v : v1[j]);
                    i1[j] = g0 ? i0[j] : (g1 ? n : i1[j]);
                    v0[j] = g0 ? v : v0[j];
                    i0[j] = g0 ? n : i0[j];
                }
            }
            // butterfly merge across the 16 col-lanes
#pragma unroll
            for (int m = 1; m < 16; m <<= 1) {
#pragma unroll
                for (int j = 0; j < 4; ++j) {
                    float ov0 = __shfl_xor(v0[j], m, 16);
                    int   oi0 = __shfl_xor(i0[j], m, 16);
                    float ov1 = __shfl_xor(v1[j], m, 16);
                    int   oi1 = __shfl_xor(i1[j], m, 16);
                    bool a = ov0 > v0[j];
                    float w0 = a ? ov0 : v0[j]; int w0i = a ? oi0 : i0[j];
                    float s0 = a ? v0[j] : ov0; int s0i = a ? i0[j] : oi0;
                    bool bgt = ov1 > v1[j];
                    float w1 = bgt ? ov1 : v1[j]; int w1i = bgt ? oi1 : i1[j];
                    bool c2 = w1 > s0;
                    v0[j] = w0; i0[j] = w0i;
                    v1[j] = c2 ? w1 : s0; i1[j] = c2 ? w1i : s0i;
                }
            }
            if (col == 0) {
#pragma unroll
                for (int j = 0; j < 4; ++j) {
                    int row = Mt * 16 + kg * 4 + j;
                    cand_v[row][wid][0] = v0[j]; cand_i[row][wid][0] = i0[j];
                    cand_v[row][wid][1] = v1[j]; cand_i[row][wid][1] = i1[j];
                }
            }
        }
    }
    __syncthreads();

    // ---------------- phase 3b: per-row top-4 of 16, sorted by n ascending
    if (t < 32) {
        float vv[16]; int ii[16];
#pragma unroll
        for (int w = 0; w < 8; ++w) {
            vv[w * 2] = cand_v[t][w][0];     ii[w * 2] = cand_i[t][w][0];
            vv[w * 2 + 1] = cand_v[t][w][1]; ii[w * 2 + 1] = cand_i[t][w][1];
        }
        int sel[4];
#pragma unroll
        for (int c = 0; c < 4; ++c) {
            float bv = -3.4e38f; int bj = 0;
#pragma unroll
            for (int q = 0; q < 16; ++q)
                if (vv[q] > bv) { bv = vv[q]; bj = q; }
            sel[c] = ii[bj];
            vv[bj] = -3.4e38f;
        }
        // sort sel[0..3] ascending (n) for first-max semantics
#pragma unroll
        for (int a = 0; a < 3; ++a)
#pragma unroll
            for (int bq = 0; bq < 3 - a; ++bq)
                if (sel[bq] > sel[bq + 1]) { int tmp = sel[bq]; sel[bq] = sel[bq + 1]; sel[bq + 1] = tmp; }
#pragma unroll
        for (int c = 0; c < 4; ++c) c4i[t][c] = sel[c];
    }
    __syncthreads();

    // ---------------- phase 3c: exact f32 seq-FMA chains on candidates (bit-identical to validated scan)
    if (t < 128) {
        int row = t >> 2, c = t & 3;
        int n = c4i[row][c];
        const float* hr = &hsm[row * 264];
        const float* cr = cbn + (size_t)n * HH;
        float a0 = 0.f;
#pragma unroll 4
        for (int k = 0; k < HH; k += 4) {
            float4 cv = *(const float4*)(cr + k);
            float4 hv = *(const float4*)&hr[k];
            a0 = fmaf(hv.x, cv.x, a0); a0 = fmaf(hv.y, cv.y, a0);
            a0 = fmaf(hv.z, cv.z, a0); a0 = fmaf(hv.w, cv.w, a0);
        }
        exv[row][c] = a0;
    }
    __syncthreads();
    if (t < 32) {
        float bv = -3.4e38f; int bi = 0;
#pragma unroll
        for (int c = 0; c < 4; ++c) {
            float v = exv[t][c];
            int n = c4i[t][c];
            if (v > bv) { bv = v; bi = n; }   // candidates n-ascending; strict > = first max
        }
        ind_sm[t] = bi;
        inds_i[b * LL + l0 + t] = bi;
    }
    __syncthreads();

    // ---------------- phase 4: loss partial (validated)
    {
        int rr = t >> 4, kg2 = t & 15;
        const float* cq2 = cbn + (size_t)ind_sm[rr] * HH;
        const float* hr = &hsm[rr * 264];
        float s = 0.f;
#pragma unroll
        for (int k = kg2 * 16; k < kg2 * 16 + 16; k += 4) {
            float4 cv = *(const float4*)(cq2 + k);
            float4 hv = *(const float4*)(hr + k);
            float e0 = cv.x - hv.x, e1 = cv.y - hv.y;
            float e2 = cv.z - hv.z, e3 = cv.w - hv.w;
            s = fmaf(e0, e0, s); s = fmaf(e1, e1, s);
            s = fmaf(e2, e2, s); s = fmaf(e3, e3, s);
        }
        s = breduce512_f32(s, sbuf);
        if (t == 0) partials[bid] = s;
    }
}

// ---------------------------------------------------------------- loss final (1024 partials)
__global__ __launch_bounds__(256) void loss_final_kernel(const float* __restrict__ partials,
                                                         float* __restrict__ out_f32) {
    __shared__ double dbuf[8];
    const int t = threadIdx.x;
    double v = ((double)partials[t] + (double)partials[t + 256]) +
               ((double)partials[t + 512] + (double)partials[t + 768]);
    double s = breduce256_f64(v, dbuf);
    if (t == 0) {
        double mean = s / (double)((size_t)BB * LL * HH);
        out_f32[LOSS_OFF] = (float)(mean * 1.25);
    }
}

// ---------------------------------------------------------------- inds epilogue
__global__ __launch_bounds__(256) void epilogue_kernel(const int* __restrict__ inds_i,
                                                       float* __restrict__ out_f32) {
    int idx = blockIdx.x * 256 + threadIdx.x;
    if (idx < BB * LL) out_f32[IND_OFF + idx] = (float)inds_i[idx];
}

// ---------------------------------------------------------------- gemm_out (unchanged)
__global__ __launch_bounds__(256) void gemm_out_kernel(const float* __restrict__ cbn,
                                                       const int* __restrict__ inds_i,
                                                       const float* __restrict__ woT,
                                                       float* __restrict__ out_f32) {
    __shared__ float zqT[32][68];
    __shared__ float wo[32][64];
    __shared__ int inds_s[64];
    const int b = blockIdx.z;
    const int d0 = blockIdx.y * 64;
    const int l0 = blockIdx.x * 64;
    const int t = threadIdx.x;
    const int tl = t & 15, td = t >> 4;
    if (t < 64) {
        int ii = inds_i[b * LL + l0 + t];
        inds_s[t] = min(max(ii, 0), NN - 1);
    }
    float acc[4][4];
#pragma unroll
    for (int i = 0; i < 4; ++i)
#pragma unroll
        for (int j = 0; j < 4; ++j) acc[i][j] = 0.f;
    for (int k0 = 0; k0 < HH; k0 += 32) {
        __syncthreads();
#pragma unroll
        for (int r = 0; r < 2; ++r) {
            int idx = r * 256 + t;
            int li = idx >> 3, k4 = idx & 7;
            float4 v = *(const float4*)(cbn + (size_t)inds_s[li] * HH + k0 + k4 * 4);
            zqT[k4 * 4 + 0][li] = v.x;
            zqT[k4 * 4 + 1][li] = v.y;
            zqT[k4 * 4 + 2][li] = v.z;
            zqT[k4 * 4 + 3][li] = v.w;
        }
#pragma unroll
        for (int r = 0; r < 2; ++r) {
            int idx = r * 256 + t;
            int kk = idx >> 4, d4 = idx & 15;
            *(float4*)&wo[kk][d4 * 4] = *(const float4*)(woT + (size_t)(k0 + kk) * DD + d0 + d4 * 4);
        }
        __syncthreads();
#pragma unroll 8
        for (int kk = 0; kk < 32; ++kk) {
            float4 zv = *(const float4*)&zqT[kk][tl * 4];
            float4 wv = *(const float4*)&wo[kk][td * 4];
            float zz[4] = {zv.x, zv.y, zv.z, zv.w};
            float ww[4] = {wv.x, wv.y, wv.z, wv.w};
#pragma unroll
            for (int il = 0; il < 4; ++il)
#pragma unroll
                for (int jd = 0; jd < 4; ++jd)
                    acc[il][jd] = fmaf(zz[il], ww[jd], acc[il][jd]);
        }
    }
    const float SQ256 = sqrtf(256.0f);
#pragma unroll
    for (int jd = 0; jd < 4; ++jd) {
        int d = d0 + td * 4 + jd;
        float4 v;
        v.x = acc[0][jd] / SQ256;
        v.y = acc[1][jd] / SQ256;
        v.z = acc[2][jd] / SQ256;
        v.w = acc[3][jd] / SQ256;
        *(float4*)(out_f32 + ((size_t)b * DD + d) * LL + l0 + tl * 4) = v;
    }
}

extern "C" void kernel_launch(void* const* d_in, const int* in_sizes, int n_in,
                              void* d_out, int out_size, void* d_ws, size_t ws_size,
                              hipStream_t stream) {
    const float* z        = (const float*)d_in[0];
    const float* w_in     = (const float*)d_in[1];
    const float* codebook = (const float*)d_in[2];
    const float* w_out    = (const float*)d_in[3];

    char* ws = (char*)d_ws;
    size_t off = 0;
    float* whT = (float*)(ws + off); off += (size_t)DD * HH * 4;        // 512 KB
    float* cbn = (float*)(ws + off); off += (size_t)NN * HH * 4;        // 2 MB
    float* woT = (float*)(ws + off); off += (size_t)HH * DD * 4;        // 512 KB
    int* inds_i = (int*)(ws + off);  off += (size_t)BB * LL * 4;        // 128 KB
    float* partials = (float*)(ws + off); off += 1024 * 4;              // 4 KB
    u16* cb_hi = (u16*)(ws + off); off += (size_t)NN * HH * 2;          // 1 MB
    u16* cb_lo = (u16*)(ws + off); off += (size_t)NN * HH * 2;          // 1 MB

    float* out_f32 = (float*)d_out;

    prep_kernel<<<HH + DD + NN, 256, 0, stream>>>(w_in, codebook, w_out, whT, cbn, woT, cb_hi, cb_lo);
    fused_kernel<<<dim3(LL / 32, BB), 512, 0, stream>>>(z, whT, cbn, cb_hi, cb_lo, inds_i, partials);
    loss_final_kernel<<<1, 256, 0, stream>>>(partials, out_f32);
    epilogue_kernel<<<(BB * LL + 255) / 256, 256, 0, stream>>>(inds_i, out_f32);
    gemm_out_kernel<<<dim3(LL / 64, DD / 64, BB), 256, 0, stream>>>(cbn, inds_i, woT, out_f32);
}

// Round 10
// 412.059 us; speedup vs baseline: 9.1290x; 1.6624x over previous
//
#include <hip/hip_runtime.h>
#include <hip/hip_bf16.h>

#pragma clang fp contract(off)

#define BB 8
#define DD 512
#define LL 4096
#define HH 256
#define NN 2048
#define FEPS 1.1920928955078125e-07f

#define IND_OFF ((size_t)BB * DD * LL)            // 16777216
#define LOSS_OFF (IND_OFF + (size_t)BB * LL)      // 16809984

typedef unsigned short u16;
typedef __attribute__((ext_vector_type(8))) short s8v;     // 8 bf16
typedef __attribute__((ext_vector_type(4))) float f32x4;

__device__ __forceinline__ u16 bf16bits(float x) {
    __hip_bfloat16 h = __float2bfloat16(x);
    return *reinterpret_cast<u16*>(&h);
}

// ---------------------------------------------------------------- numpy-exact pairwise sums
__device__ __forceinline__ float npy_pw128(const float* a) {
    float r0 = 0.f, r1 = 0.f, r2 = 0.f, r3 = 0.f, r4 = 0.f, r5 = 0.f, r6 = 0.f, r7 = 0.f;
    for (int i = 0; i < 128; i += 8) {
        r0 += a[i + 0]; r1 += a[i + 1]; r2 += a[i + 2]; r3 += a[i + 3];
        r4 += a[i + 4]; r5 += a[i + 5]; r6 += a[i + 6]; r7 += a[i + 7];
    }
    return ((r0 + r1) + (r2 + r3)) + ((r4 + r5) + (r6 + r7));
}

__device__ __forceinline__ float npy_pw128_sq(const float* a) {
    float r0 = 0.f, r1 = 0.f, r2 = 0.f, r3 = 0.f, r4 = 0.f, r5 = 0.f, r6 = 0.f, r7 = 0.f;
    for (int i = 0; i < 128; i += 8) {
        float p0 = a[i + 0] * a[i + 0]; float p1 = a[i + 1] * a[i + 1];
        float p2 = a[i + 2] * a[i + 2]; float p3 = a[i + 3] * a[i + 3];
        float p4 = a[i + 4] * a[i + 4]; float p5 = a[i + 5] * a[i + 5];
        float p6 = a[i + 6] * a[i + 6]; float p7 = a[i + 7] * a[i + 7];
        r0 += p0; r1 += p1; r2 += p2; r3 += p3;
        r4 += p4; r5 += p5; r6 += p6; r7 += p7;
    }
    return ((r0 + r1) + (r2 + r3)) + ((r4 + r5) + (r6 + r7));
}

__device__ inline float breduce512_f32(float v, float* sbuf) {
    for (int off = 32; off > 0; off >>= 1) v += __shfl_down(v, off, 64);
    int wid = threadIdx.x >> 6;
    if ((threadIdx.x & 63) == 0) sbuf[wid] = v;
    __syncthreads();
    if (threadIdx.x == 0) {
        float r = 0.f;
#pragma unroll
        for (int i = 0; i < 8; ++i) r += sbuf[i];
        sbuf[0] = r;
    }
    __syncthreads();
    float r = sbuf[0];
    __syncthreads();
    return r;
}

__device__ inline double breduce256_f64(double v, double* dbuf) {
    for (int off = 32; off > 0; off >>= 1) v += __shfl_down(v, off, 64);
    int wid = threadIdx.x >> 6, lane = threadIdx.x & 63;
    if (lane == 0) dbuf[wid] = v;
    __syncthreads();
    if (threadIdx.x == 0) dbuf[0] = dbuf[0] + dbuf[1] + dbuf[2] + dbuf[3];
    __syncthreads();
    double r = dbuf[0];
    __syncthreads();
    return r;
}

// ---------------------------------------------------------------- prep (validated; bf16 hi of cbn)
__global__ __launch_bounds__(256) void prep_kernel(const float* __restrict__ w_in,
                                                   const float* __restrict__ codebook,
                                                   const float* __restrict__ w_out,
                                                   float* __restrict__ whT,
                                                   float* __restrict__ cbn,
                                                   float* __restrict__ woT,
                                                   u16* __restrict__ cb_hi) {
    __shared__ float srow[512];
    __shared__ float sden;
    const int blk = blockIdx.x;
    const int t = threadIdx.x;
    if (blk < HH) {
        const float* row = w_in + (size_t)blk * DD;
        float a = row[t], b = row[t + 256];
        srow[t] = a * a;
        srow[t + 256] = b * b;
        __syncthreads();
        if (t == 0) {
            float ss = (npy_pw128(srow) + npy_pw128(srow + 128)) +
                       (npy_pw128(srow + 256) + npy_pw128(srow + 384));
            sden = sqrtf(ss) + FEPS;
        }
        __syncthreads();
        float den = sden;
        whT[(size_t)t * HH + blk] = a / den;
        whT[(size_t)(t + 256) * HH + blk] = b / den;
    } else if (blk < HH + DD) {
        const int d = blk - HH;
        const float* row = w_out + (size_t)d * HH;
        float a = row[t];
        srow[t] = a * a;
        __syncthreads();
        if (t == 0) {
            float ss = npy_pw128(srow) + npy_pw128(srow + 128);
            sden = sqrtf(ss) + FEPS;
        }
        __syncthreads();
        woT[(size_t)t * DD + d] = a / sden;
    } else {
        const int n = blk - HH - DD;
        const float* row = codebook + (size_t)n * HH;
        float a = row[t];
        srow[t] = a * a;
        __syncthreads();
        if (t == 0) {
            float ss = npy_pw128(srow) + npy_pw128(srow + 128);
            float m = ss / 256.0f;
            sden = 1.0f / sqrtf(m + FEPS);
        }
        __syncthreads();
        float v = a * sden;
        cbn[(size_t)n * HH + t] = v;
        cb_hi[(size_t)n * HH + t] = bf16bits(v);
    }
}

// ---------------------------------------------------------------- fused: 64-row blocks
// grid (LL/64, BB), 512 threads. Decision arithmetic bit-identical to validated rounds 7-9.
__global__ __launch_bounds__(512, 2) void fused_kernel(const float* __restrict__ z,
                                                       const float* __restrict__ whT,
                                                       const float* __restrict__ cbn,
                                                       const u16* __restrict__ cb_hi,
                                                       int* __restrict__ inds_i,
                                                       float* __restrict__ partials) {
    __shared__ float smem[16896];       // union: phase1 zT[32][64]@0 + wT[32][256]@2048 | hsm[64][264]@0
    __shared__ u16   hhi[64 * 264];     // bf16 hi of h_n
    __shared__ float cand_v[64][8][2];
    __shared__ int   cand_i[64][8][2];
    __shared__ int   c4i[64][4];
    __shared__ float exv[64][4];
    __shared__ float rtmp[128];
    __shared__ float scl[64];
    __shared__ int   ind_sm[64];
    __shared__ float sbuf[8];

    float* zT  = smem;              // [kk][l]   stride 64
    float* wT  = smem + 2048;       // [kk][h]   stride 256
    float* hsm = smem;              // [row][k]  stride 264

    const int b = blockIdx.y;
    const int l0 = blockIdx.x * 64;
    const int t = threadIdx.x;
    const int tl = t & 15, th = t >> 4;   // rows tl*4+il ; h-dims th*8+j
    const int bid = blockIdx.y * gridDim.x + blockIdx.x;

    // ---------------- phase 1: f32 seq-FMA GEMM (validated round-7 structure)
    float acc[4][8];
#pragma unroll
    for (int i = 0; i < 4; ++i)
#pragma unroll
        for (int j = 0; j < 8; ++j) acc[i][j] = 0.f;
    const float* zb = z + (size_t)b * DD * LL;
    for (int d0 = 0; d0 < DD; d0 += 32) {
        __syncthreads();
        {   // zT: 2048 floats = 512 x float4
            int kk = t >> 4, c4 = t & 15;
            *(float4*)&zT[kk * 64 + c4 * 4] =
                *(const float4*)(zb + (size_t)(d0 + kk) * LL + l0 + c4 * 4);
        }
#pragma unroll
        for (int r = 0; r < 4; ++r) {   // wT: 8192 floats = 512 x 4 float4
            int idx = r * 512 + t;
            int kk = idx >> 6, h4 = idx & 63;
            *(float4*)&wT[kk * 256 + h4 * 4] =
                *(const float4*)(whT + (size_t)(d0 + kk) * HH + h4 * 4);
        }
        __syncthreads();
#pragma unroll 8
        for (int kk = 0; kk < 32; ++kk) {
            float4 zv = *(const float4*)&zT[kk * 64 + tl * 4];
            float zz[4] = {zv.x, zv.y, zv.z, zv.w};
            float4 wa = *(const float4*)&wT[kk * 256 + th * 8];
            float4 wb = *(const float4*)&wT[kk * 256 + th * 8 + 4];
            float ww[8] = {wa.x, wa.y, wa.z, wa.w, wb.x, wb.y, wb.z, wb.w};
#pragma unroll
            for (int il = 0; il < 4; ++il)
#pragma unroll
                for (int j = 0; j < 8; ++j)
                    acc[il][j] = fmaf(zz[il], ww[j], acc[il][j]);
        }
    }
    __syncthreads();   // phase-1 LDS reads complete before hsm overwrite

    // ---------------- phase 2: h -> hsm; npy rms; h_n in place (validated)
    const float SQ512 = sqrtf(512.0f);
#pragma unroll
    for (int il = 0; il < 4; ++il) {
        int row = tl * 4 + il;
#pragma unroll
        for (int j = 0; j < 8; ++j)
            hsm[row * 264 + th * 8 + j] = acc[il][j] / SQ512;
    }
    __syncthreads();
    if (t < 128) {
        int row = t >> 1, half = t & 1;
        rtmp[t] = npy_pw128_sq(&hsm[row * 264 + half * 128]);
    }
    __syncthreads();
    if (t < 64) {
        float ss = rtmp[t * 2] + rtmp[t * 2 + 1];
        float m = ss / 256.0f;
        scl[t] = 1.0f / sqrtf(m + FEPS);
    }
    __syncthreads();
    {   // h_n = h * s in place + bf16 hi split: 512 threads x 32 elems
        int row = t >> 3, c0 = (t & 7) * 32;
        float s = scl[row];
        float* hp = &hsm[row * 264 + c0];
        u16* hh = &hhi[row * 264 + c0];
#pragma unroll
        for (int k = 0; k < 32; ++k) {
            float x = hp[k] * s;
            hp[k] = x;
            hh[k] = bf16bits(x);
        }
    }
    __syncthreads();

    // ---------------- phase 3a: MFMA hi-only screen -> per-wave top-2 per row
    {
        const int lane = t & 63;
        const int wid = t >> 6;          // 8 waves, 256 codes each
        const int col = lane & 15;
        const int kg = lane >> 4;        // k = s*32 + kg*8 + e
#pragma unroll 1
        for (int mg = 0; mg < 2; ++mg) {
            s8v ah[2][8];
#pragma unroll
            for (int mt = 0; mt < 2; ++mt) {
                int arow = (mg * 2 + mt) * 16 + col;
#pragma unroll
                for (int s = 0; s < 8; ++s)
                    ah[mt][s] = *(const s8v*)&hhi[arow * 264 + s * 32 + kg * 8];
            }
            float v0[2][4], v1[2][4]; int i0[2][4], i1[2][4];
#pragma unroll
            for (int mt = 0; mt < 2; ++mt)
#pragma unroll
                for (int j = 0; j < 4; ++j) {
                    v0[mt][j] = -3.4e38f; v1[mt][j] = -3.4e38f;
                    i0[mt][j] = 0; i1[mt][j] = 0;
                }
#pragma unroll 1
            for (int it = 0; it < 16; ++it) {
                const int n0 = (wid * 16 + it) * 16;
                const u16* cbh = cb_hi + (size_t)(n0 + col) * HH;
                f32x4 a0 = {0.f, 0.f, 0.f, 0.f}, a1 = a0;
#pragma unroll
                for (int s = 0; s < 8; ++s) {
                    s8v bh = *(const s8v*)(cbh + s * 32 + kg * 8);
                    a0 = __builtin_amdgcn_mfma_f32_16x16x32_bf16(ah[0][s], bh, a0, 0, 0, 0);
                    a1 = __builtin_amdgcn_mfma_f32_16x16x32_bf16(ah[1][s], bh, a1, 0, 0, 0);
                }
                const int n = n0 + col;
#pragma unroll
                for (int j = 0; j < 4; ++j) {
                    {
                        float v = a0[j];
                        bool g0 = v > v0[0][j], g1 = v > v1[0][j];
                        v1[0][j] = g0 ? v0[0][j] : (g1 ? v : v1[0][j]);
                        i1[0][j] = g0 ? i0[0][j] : (g1 ? n : i1[0][j]);
                        v0[0][j] = g0 ? v : v0[0][j];
                        i0[0][j] = g0 ? n : i0[0][j];
                    }
                    {
                        float v = a1[j];
                        bool g0 = v > v0[1][j], g1 = v > v1[1][j];
                        v1[1][j] = g0 ? v0[1][j] : (g1 ? v : v1[1][j]);
                        i1[1][j] = g0 ? i0[1][j] : (g1 ? n : i1[1][j]);
                        v0[1][j] = g0 ? v : v0[1][j];
                        i0[1][j] = g0 ? n : i0[1][j];
                    }
                }
            }
            // butterfly merge across the 16 col-lanes
#pragma unroll
            for (int m = 1; m < 16; m <<= 1) {
#pragma unroll
                for (int mt = 0; mt < 2; ++mt)
#pragma unroll
                    for (int j = 0; j < 4; ++j) {
                        float ov0 = __shfl_xor(v0[mt][j], m, 16);
                        int   oi0 = __shfl_xor(i0[mt][j], m, 16);
                        float ov1 = __shfl_xor(v1[mt][j], m, 16);
                        int   oi1 = __shfl_xor(i1[mt][j], m, 16);
                        bool a = ov0 > v0[mt][j];
                        float w0 = a ? ov0 : v0[mt][j]; int w0i = a ? oi0 : i0[mt][j];
                        float s0 = a ? v0[mt][j] : ov0; int s0i = a ? i0[mt][j] : oi0;
                        bool bgt = ov1 > v1[mt][j];
                        float w1 = bgt ? ov1 : v1[mt][j]; int w1i = bgt ? oi1 : i1[mt][j];
                        bool c2 = w1 > s0;
                        v0[mt][j] = w0; i0[mt][j] = w0i;
                        v1[mt][j] = c2 ? w1 : s0; i1[mt][j] = c2 ? w1i : s0i;
                    }
            }
            if (col == 0) {
#pragma unroll
                for (int mt = 0; mt < 2; ++mt)
#pragma unroll
                    for (int j = 0; j < 4; ++j) {
                        int row = (mg * 2 + mt) * 16 + kg * 4 + j;
                        cand_v[row][wid][0] = v0[mt][j]; cand_i[row][wid][0] = i0[mt][j];
                        cand_v[row][wid][1] = v1[mt][j]; cand_i[row][wid][1] = i1[mt][j];
                    }
            }
        }
    }
    __syncthreads();

    // ---------------- phase 3b: per-row top-4 of 16, sorted by n ascending
    if (t < 64) {
        float vv[16]; int ii[16];
#pragma unroll
        for (int w = 0; w < 8; ++w) {
            vv[w * 2] = cand_v[t][w][0];     ii[w * 2] = cand_i[t][w][0];
            vv[w * 2 + 1] = cand_v[t][w][1]; ii[w * 2 + 1] = cand_i[t][w][1];
        }
        int sel[4];
#pragma unroll
        for (int c = 0; c < 4; ++c) {
            float bv = -3.4e38f; int bj = 0;
#pragma unroll
            for (int q = 0; q < 16; ++q)
                if (vv[q] > bv) { bv = vv[q]; bj = q; }
            sel[c] = ii[bj];
            vv[bj] = -3.4e38f;
        }
#pragma unroll
        for (int a = 0; a < 3; ++a)
#pragma unroll
            for (int bq = 0; bq < 3 - a; ++bq)
                if (sel[bq] > sel[bq + 1]) { int tmp = sel[bq]; sel[bq] = sel[bq + 1]; sel[bq + 1] = tmp; }
#pragma unroll
        for (int c = 0; c < 4; ++c) c4i[t][c] = sel[c];
    }
    __syncthreads();

    // ---------------- phase 3c: exact f32 seq-FMA verify (bit-identical chain)
    if (t < 256) {
        int row = t >> 2, c = t & 3;
        int n = c4i[row][c];
        const float* hr = &hsm[row * 264];
        const float* cr = cbn + (size_t)n * HH;
        float a0 = 0.f;
#pragma unroll 4
        for (int k = 0; k < HH; k += 4) {
            float4 cv = *(const float4*)(cr + k);
            float4 hv = *(const float4*)&hr[k];
            a0 = fmaf(hv.x, cv.x, a0); a0 = fmaf(hv.y, cv.y, a0);
            a0 = fmaf(hv.z, cv.z, a0); a0 = fmaf(hv.w, cv.w, a0);
        }
        exv[row][c] = a0;
    }
    __syncthreads();
    if (t < 64) {
        float bv = -3.4e38f; int bi = 0;
#pragma unroll
        for (int c = 0; c < 4; ++c) {
            float v = exv[t][c];
            int n = c4i[t][c];
            if (v > bv) { bv = v; bi = n; }   // candidates n-ascending; strict > = first max
        }
        ind_sm[t] = bi;
        inds_i[b * LL + l0 + t] = bi;
    }
    __syncthreads();

    // ---------------- phase 4: loss partial (validated round-7 structure)
    {
        int rr = t >> 3, kg2 = t & 7;
        const float* cq2 = cbn + (size_t)ind_sm[rr] * HH;
        const float* hr = &hsm[rr * 264];
        float s = 0.f;
#pragma unroll
        for (int k = kg2 * 32; k < kg2 * 32 + 32; k += 4) {
            float4 cv = *(const float4*)(cq2 + k);
            float4 hv = *(const float4*)(hr + k);
            float e0 = cv.x - hv.x, e1 = cv.y - hv.y;
            float e2 = cv.z - hv.z, e3 = cv.w - hv.w;
            s = fmaf(e0, e0, s); s = fmaf(e1, e1, s);
            s = fmaf(e2, e2, s); s = fmaf(e3, e3, s);
        }
        s = breduce512_f32(s, sbuf);
        if (t == 0) partials[bid] = s;
    }
}

// ---------------------------------------------------------------- loss final (512 partials)
__global__ __launch_bounds__(256) void loss_final_kernel(const float* __restrict__ partials,
                                                         float* __restrict__ out_f32) {
    __shared__ double dbuf[8];
    const int t = threadIdx.x;
    double v = (double)partials[t] + (double)partials[t + 256];
    double s = breduce256_f64(v, dbuf);
    if (t == 0) {
        double mean = s / (double)((size_t)BB * LL * HH);
        out_f32[LOSS_OFF] = (float)(mean * 1.25);
    }
}

// ---------------------------------------------------------------- inds epilogue
__global__ __launch_bounds__(256) void epilogue_kernel(const int* __restrict__ inds_i,
                                                       float* __restrict__ out_f32) {
    int idx = blockIdx.x * 256 + threadIdx.x;
    if (idx < BB * LL) out_f32[IND_OFF + idx] = (float)inds_i[idx];
}

// ---------------------------------------------------------------- gemm_out (unchanged)
__global__ __launch_bounds__(256) void gemm_out_kernel(const float* __restrict__ cbn,
                                                       const int* __restrict__ inds_i,
                                                       const float* __restrict__ woT,
                                                       float* __restrict__ out_f32) {
    __shared__ float zqT[32][68];
    __shared__ float wo[32][64];
    __shared__ int inds_s[64];
    const int b = blockIdx.z;
    const int d0 = blockIdx.y * 64;
    const int l0 = blockIdx.x * 64;
    const int t = threadIdx.x;
    const int tl = t & 15, td = t >> 4;
    if (t < 64) {
        int ii = inds_i[b * LL + l0 + t];
        inds_s[t] = min(max(ii, 0), NN - 1);
    }
    float acc[4][4];
#pragma unroll
    for (int i = 0; i < 4; ++i)
#pragma unroll
        for (int j = 0; j < 4; ++j) acc[i][j] = 0.f;
    for (int k0 = 0; k0 < HH; k0 += 32) {
        __syncthreads();
#pragma unroll
        for (int r = 0; r < 2; ++r) {
            int idx = r * 256 + t;
            int li = idx >> 3, k4 = idx & 7;
            float4 v = *(const float4*)(cbn + (size_t)inds_s[li] * HH + k0 + k4 * 4);
            zqT[k4 * 4 + 0][li] = v.x;
            zqT[k4 * 4 + 1][li] = v.y;
            zqT[k4 * 4 + 2][li] = v.z;
            zqT[k4 * 4 + 3][li] = v.w;
        }
#pragma unroll
        for (int r = 0; r < 2; ++r) {
            int idx = r * 256 + t;
            int kk = idx >> 4, d4 = idx & 15;
            *(float4*)&wo[kk][d4 * 4] = *(const float4*)(woT + (size_t)(k0 + kk) * DD + d0 + d4 * 4);
        }
        __syncthreads();
#pragma unroll 8
        for (int kk = 0; kk < 32; ++kk) {
            float4 zv = *(const float4*)&zqT[kk][tl * 4];
            float4 wv = *(const float4*)&wo[kk][td * 4];
            float zz[4] = {zv.x, zv.y, zv.z, zv.w};
            float ww[4] = {wv.x, wv.y, wv.z, wv.w};
#pragma unroll
            for (int il = 0; il < 4; ++il)
#pragma unroll
                for (int jd = 0; jd < 4; ++jd)
                    acc[il][jd] = fmaf(zz[il], ww[jd], acc[il][jd]);
        }
    }
    const float SQ256 = sqrtf(256.0f);
#pragma unroll
    for (int jd = 0; jd < 4; ++jd) {
        int d = d0 + td * 4 + jd;
        float4 v;
        v.x = acc[0][jd] / SQ256;
        v.y = acc[1][jd] / SQ256;
        v.z = acc[2][jd] / SQ256;
        v.w = acc[3][jd] / SQ256;
        *(float4*)(out_f32 + ((size_t)b * DD + d) * LL + l0 + tl * 4) = v;
    }
}

extern "C" void kernel_launch(void* const* d_in, const int* in_sizes, int n_in,
                              void* d_out, int out_size, void* d_ws, size_t ws_size,
                              hipStream_t stream) {
    const float* z        = (const float*)d_in[0];
    const float* w_in     = (const float*)d_in[1];
    const float* codebook = (const float*)d_in[2];
    const float* w_out    = (const float*)d_in[3];

    char* ws = (char*)d_ws;
    size_t off = 0;
    float* whT = (float*)(ws + off); off += (size_t)DD * HH * 4;        // 512 KB
    float* cbn = (float*)(ws + off); off += (size_t)NN * HH * 4;        // 2 MB
    float* woT = (float*)(ws + off); off += (size_t)HH * DD * 4;        // 512 KB
    int* inds_i = (int*)(ws + off);  off += (size_t)BB * LL * 4;        // 128 KB
    float* partials = (float*)(ws + off); off += 512 * 4;               // 2 KB
    u16* cb_hi = (u16*)(ws + off); off += (size_t)NN * HH * 2;          // 1 MB

    float* out_f32 = (float*)d_out;

    prep_kernel<<<HH + DD + NN, 256, 0, stream>>>(w_in, codebook, w_out, whT, cbn, woT, cb_hi);
    fused_kernel<<<dim3(LL / 64, BB), 512, 0, stream>>>(z, whT, cbn, cb_hi, inds_i, partials);
    loss_final_kernel<<<1, 256, 0, stream>>>(partials, out_f32);
    epilogue_kernel<<<(BB * LL + 255) / 256, 256, 0, stream>>>(inds_i, out_f32);
    gemm_out_kernel<<<dim3(LL / 64, DD / 64, BB), 256, 0, stream>>>(cbn, inds_i, woT, out_f32);
}